// Round 7
// baseline (1540.576 us; speedup 1.0000x reference)
//
#include <hip/hip_runtime.h>
#include <cstdint>

typedef long long i64;
typedef unsigned short us16;
typedef unsigned int u32;
typedef __attribute__((ext_vector_type(8))) short bf16x8;   // 8 bf16 in 4 VGPRs
typedef __attribute__((ext_vector_type(4))) float f32x4;

#define D_    1024
#define H_    16
#define DH_   64
#define DC_   256
#define E_    8
#define DFF_  2048
#define B_    2
#define S_    2048
#define T_    (B_*S_)     // 4096 tokens

// ---- workspace regions (BYTE offsets), serially time-multiplexed. High-water ~139.5 MB ----
// A [0,16M):  h1 f32 (LN1 out) -> Kt bf16 [0,8M) -> h2 bf16 [0,8M) -> moeB f32
// B [16,32M): q f32 -> attn_proj f32 -> moeA f32
// C [32,48M): k f32 -> attn-out f32 -> hid rows 0..4095 (bf16, spans C+D)
// D [48,64M): v f32 -> hid rows 4096..8191
#define WOFF_A     0LL
#define WOFF_B     (16LL<<20)
#define WOFF_C     (32LL<<20)
#define WOFF_D     (48LL<<20)
#define WOFF_WSPL  (64LL<<20)    // split MLA weights hi/lo (11 MB)
#define WOFF_W1T   (75LL<<20)    // [8][2048][1024] bf16 (32 MB)
#define WOFF_W2T   (107LL<<20)   // [8][1024][2048] bf16 (32 MB)
#define WOFF_LISTS (139LL<<20)   // cnt/base/idx/tokinfo/tokgate (~0.4 MB)

__device__ __forceinline__ float wsum(float v) {
#pragma unroll
    for (int o = 32; o; o >>= 1) v += __shfl_xor(v, o);
    return v;
}
__device__ __forceinline__ float wmax(float v) {
#pragma unroll
    for (int o = 32; o; o >>= 1) v = fmaxf(v, __shfl_xor(v, o));
    return v;
}
__device__ __forceinline__ float silu_f(float x) { return x / (1.f + __expf(-x)); }
__device__ __forceinline__ us16 f2b(float f) {          // fp32 -> bf16 RNE
    u32 u = __builtin_bit_cast(u32, f);
    u += 0x7fffu + ((u >> 16) & 1u);
    return (us16)(u >> 16);
}
__device__ __forceinline__ float b2f(us16 b) {
    u32 u = ((u32)b) << 16;
    return __builtin_bit_cast(float, u);
}
// 8 f32 -> hi/lo bf16 packs (split representation: v = hi + lo + O(2^-18 v))
__device__ __forceinline__ void split8(float4 x, float4 y, uint4& hi, uint4& lo) {
    float f[8] = {x.x, x.y, x.z, x.w, y.x, y.y, y.z, y.w};
    u32 hw[4], lw[4];
#pragma unroll
    for (int i = 0; i < 4; ++i) {
        us16 h0 = f2b(f[2 * i]),     h1 = f2b(f[2 * i + 1]);
        us16 l0 = f2b(f[2 * i] - b2f(h0));
        us16 l1 = f2b(f[2 * i + 1] - b2f(h1));
        hw[i] = (u32)h0 | ((u32)h1 << 16);
        lw[i] = (u32)l0 | ((u32)l1 << 16);
    }
    hi = make_uint4(hw[0], hw[1], hw[2], hw[3]);
    lo = make_uint4(lw[0], lw[1], lw[2], lw[3]);
}

// ---------------- weight fp32[K][N] -> bf16 out[N][K] (transpose + convert) ----------------
__global__ __launch_bounds__(256) void wtrans_kernel(
    const float* __restrict__ in, us16* __restrict__ out, int K, int N)
{
    in  += (i64)blockIdx.z * K * N;
    out += (i64)blockIdx.z * K * N;
    __shared__ float t[32][33];
    int n0 = blockIdx.x * 32, k0 = blockIdx.y * 32;
    int c = threadIdx.x & 31, r8 = threadIdx.x >> 5;
#pragma unroll
    for (int i = 0; i < 4; ++i)
        t[i * 8 + r8][c] = in[(i64)(k0 + i * 8 + r8) * N + n0 + c];
    __syncthreads();
    int c2 = (threadIdx.x & 15) * 2, r16 = threadIdx.x >> 4;
#pragma unroll
    for (int it = 0; it < 2; ++it) {
        int n = it * 16 + r16;
        u32 packed = (u32)f2b(t[c2][n]) | ((u32)f2b(t[c2 + 1][n]) << 16);
        *(u32*)&out[(i64)(n0 + n) * K + k0 + c2] = packed;
    }
}

// ------------- weight fp32[K][N] -> SPLIT bf16 hi/lo [N][K] (transpose + split) -------------
__global__ __launch_bounds__(256) void wtrans_split_kernel(
    const float* __restrict__ in, us16* __restrict__ ohi, us16* __restrict__ olo, int K, int N)
{
    __shared__ float t[32][33];
    int n0 = blockIdx.x * 32, k0 = blockIdx.y * 32;
    int c = threadIdx.x & 31, r8 = threadIdx.x >> 5;
#pragma unroll
    for (int i = 0; i < 4; ++i)
        t[i * 8 + r8][c] = in[(i64)(k0 + i * 8 + r8) * N + n0 + c];
    __syncthreads();
    int c2 = (threadIdx.x & 15) * 2, r16 = threadIdx.x >> 4;
#pragma unroll
    for (int it = 0; it < 2; ++it) {
        int n = it * 16 + r16;
        float v0 = t[c2][n], v1 = t[c2 + 1][n];
        us16 h0 = f2b(v0), h1 = f2b(v1);
        us16 l0 = f2b(v0 - b2f(h0)), l1 = f2b(v1 - b2f(h1));
        *(u32*)&ohi[(i64)(n0 + n) * K + k0 + c2] = (u32)h0 | ((u32)h1 << 16);
        *(u32*)&olo[(i64)(n0 + n) * K + k0 + c2] = (u32)l0 | ((u32)l1 << 16);
    }
}

// ---------------- K f32 [T][1024] -> Kt bf16 [b*16+h][64][S] (per-head transpose) -------
__global__ __launch_bounds__(256) void ktrans_kernel(
    const float* __restrict__ kf, us16* __restrict__ Kt)
{
    int bh = blockIdx.z;                 // b*16+h
    int t0 = blockIdx.x * 32;
    int d0 = blockIdx.y * 32;
    int b = bh >> 4, h = bh & 15;
    __shared__ float tle[32][33];
    int c = threadIdx.x & 31, r8 = threadIdx.x >> 5;
#pragma unroll
    for (int i = 0; i < 4; ++i)
        tle[i * 8 + r8][c] = kf[((i64)(b * S_ + t0 + i * 8 + r8)) * D_ + h * DH_ + d0 + c];
    __syncthreads();
    int c2 = (threadIdx.x & 15) * 2, r16 = threadIdx.x >> 4;
#pragma unroll
    for (int it = 0; it < 2; ++it) {
        int dr = it * 16 + r16;
        u32 pk = (u32)f2b(tle[c2][dr]) | ((u32)f2b(tle[c2 + 1][dr]) << 16);
        *(u32*)&Kt[((i64)(bh * DH_ + d0 + dr)) * S_ + t0 + c2] = pk;
    }
}

// ------- fused (optional add) + LayerNorm; optional f32 out + optional bf16 out -------
__global__ __launch_bounds__(256) void add_ln_kernel(
    const float* __restrict__ x, const float* __restrict__ add,
    const float* __restrict__ w, const float* __restrict__ bias,
    float* __restrict__ x2out, float* __restrict__ hf32, us16* __restrict__ hout)
{
    int t = blockIdx.x;
    int tid = threadIdx.x;
    float4 v = ((const float4*)(x + (i64)t * D_))[tid];
    if (add) {
        float4 a = ((const float4*)(add + (i64)t * D_))[tid];
        v.x += a.x; v.y += a.y; v.z += a.z; v.w += a.w;
    }
    float s  = v.x + v.y + v.z + v.w;
    float ss = v.x*v.x + v.y*v.y + v.z*v.z + v.w*v.w;
    s = wsum(s); ss = wsum(ss);
    __shared__ float red[2][4];
    int wave = tid >> 6, lane = tid & 63;
    if (lane == 0) { red[0][wave] = s; red[1][wave] = ss; }
    __syncthreads();
    s  = red[0][0] + red[0][1] + red[0][2] + red[0][3];
    ss = red[1][0] + red[1][1] + red[1][2] + red[1][3];
    float mu   = s * (1.f / D_);
    float var  = ss * (1.f / D_) - mu * mu;
    float rstd = rsqrtf(var + 1e-5f);
    if (x2out) ((float4*)(x2out + (i64)t * D_))[tid] = v;
    float4 wv = ((const float4*)w)[tid];
    float4 bv = ((const float4*)bias)[tid];
    float o0 = (v.x - mu) * rstd * wv.x + bv.x;
    float o1 = (v.y - mu) * rstd * wv.y + bv.y;
    float o2 = (v.z - mu) * rstd * wv.z + bv.z;
    float o3 = (v.w - mu) * rstd * wv.w + bv.w;
    if (hf32)
        ((float4*)(hf32 + (i64)t * D_))[tid] = make_float4(o0, o1, o2, o3);
    if (hout) {
        uint2 pk;
        pk.x = (u32)f2b(o0) | ((u32)f2b(o1) << 16);
        pk.y = (u32)f2b(o2) | ((u32)f2b(o3) << 16);
        *(uint2*)&hout[(i64)t * D_ + tid * 4] = pk;
    }
}

// ------- SPLIT-precision MFMA GEMM: Cf = A(f32) @ B (B pre-split hi/lo, [N][K]) -------
// 128x128 tile, BK=32, 256 thr, 4 waves (2x2), 4x4 frags; 3 MFMA passes:
// acc += Ahi*Bhi + Ahi*Blo + Alo*Bhi  (drops lo*lo: ~2^-18 rel). A split during staging.
// Pre-gate chain must be ~f32: bf16 here flips top-2 MoE routing vs the f32 reference.
__global__ __launch_bounds__(256) void sgemm_split_kernel(
    const float* __restrict__ A, const us16* __restrict__ Bhi, const us16* __restrict__ Blo,
    float* __restrict__ Cf, int N, int Kd, int lda, int ldb, int ldc)
{
    int row0 = blockIdx.y * 128;
    int col0 = blockIdx.x * 128;
    __shared__ us16 Ash[128 * 32], Asl[128 * 32], Bsh[128 * 32], Bsl[128 * 32];
    int tid = threadIdx.x;
    int r4 = tid >> 2, sseg = tid & 3, so = sseg * 8;
    const float* a0p = A + (i64)(row0 + r4) * lda + so;
    const float* a1p = A + (i64)(row0 + r4 + 64) * lda + so;
    i64 brow0 = (i64)(col0 + r4) * ldb + so;
    i64 brow1 = brow0 + (i64)64 * ldb;
    int wa = tid * 8;

    int lane = tid & 63, w = tid >> 6;
    int wm = w >> 1, wn = w & 1;
    int cl = lane & 15, kg = lane >> 4;
    int aoff = (wm * 64 + cl) * 32 + kg * 8;
    int boff = (wn * 64 + cl) * 32 + kg * 8;

    f32x4 acc[4][4];
#pragma unroll
    for (int m = 0; m < 4; ++m)
#pragma unroll
        for (int n = 0; n < 4; ++n) {
            f32x4 z = {0.f, 0.f, 0.f, 0.f};
            acc[m][n] = z;
        }

    float4 a00 = *(const float4*)(a0p),     a01 = *(const float4*)(a0p + 4);
    float4 a10 = *(const float4*)(a1p),     a11 = *(const float4*)(a1p + 4);
    uint4 bh0 = *(const uint4*)&Bhi[brow0], bh1 = *(const uint4*)&Bhi[brow1];
    uint4 bl0 = *(const uint4*)&Blo[brow0], bl1 = *(const uint4*)&Blo[brow1];

    for (int k0 = 0; k0 < Kd; k0 += 32) {
        uint4 hi, lo;
        __syncthreads();
        split8(a00, a01, hi, lo);
        *(uint4*)&Ash[wa] = hi;  *(uint4*)&Asl[wa] = lo;
        split8(a10, a11, hi, lo);
        *(uint4*)&Ash[wa + 2048] = hi;  *(uint4*)&Asl[wa + 2048] = lo;
        *(uint4*)&Bsh[wa] = bh0;        *(uint4*)&Bsh[wa + 2048] = bh1;
        *(uint4*)&Bsl[wa] = bl0;        *(uint4*)&Bsl[wa + 2048] = bl1;
        __syncthreads();
        int kn = (k0 + 32 < Kd) ? k0 + 32 : Kd - 32;   // redundant last reload (harmless)
        a00 = *(const float4*)(a0p + kn);      a01 = *(const float4*)(a0p + kn + 4);
        a10 = *(const float4*)(a1p + kn);      a11 = *(const float4*)(a1p + kn + 4);
        bh0 = *(const uint4*)&Bhi[brow0 + kn]; bh1 = *(const uint4*)&Bhi[brow1 + kn];
        bl0 = *(const uint4*)&Blo[brow0 + kn]; bl1 = *(const uint4*)&Blo[brow1 + kn];

        bf16x8 ah[4], al[4], bh[4], bl[4];
#pragma unroll
        for (int m = 0; m < 4; ++m) {
            ah[m] = *(const bf16x8*)&Ash[aoff + m * 16 * 32];
            al[m] = *(const bf16x8*)&Asl[aoff + m * 16 * 32];
        }
#pragma unroll
        for (int n = 0; n < 4; ++n) {
            bh[n] = *(const bf16x8*)&Bsh[boff + n * 16 * 32];
            bl[n] = *(const bf16x8*)&Bsl[boff + n * 16 * 32];
        }
#pragma unroll
        for (int m = 0; m < 4; ++m)
#pragma unroll
            for (int n = 0; n < 4; ++n) {
                acc[m][n] = __builtin_amdgcn_mfma_f32_16x16x32_bf16(al[m], bh[n], acc[m][n], 0, 0, 0);
                acc[m][n] = __builtin_amdgcn_mfma_f32_16x16x32_bf16(ah[m], bl[n], acc[m][n], 0, 0, 0);
                acc[m][n] = __builtin_amdgcn_mfma_f32_16x16x32_bf16(ah[m], bh[n], acc[m][n], 0, 0, 0);
            }
    }

    // C/D layout: col = lane&15, row = (lane>>4)*4 + reg   [verified m89]
#pragma unroll
    for (int m = 0; m < 4; ++m)
#pragma unroll
        for (int j = 0; j < 4; ++j) {
            int r = row0 + wm * 64 + m * 16 + kg * 4 + j;
            i64 ro = (i64)r * ldc + col0 + wn * 64 + cl;
#pragma unroll
            for (int n = 0; n < 4; ++n)
                Cf[ro + n * 16] = acc[m][n][j];
        }
}

// ---------------- plain bf16 MFMA GEMM (MoE path): 128x128, BK=32, 4 waves ----------------
// MODE 1: A rows gathered via idx_list; Cb[base+r] = bf16(silu(acc))
// MODE 2: A rows = base[e]+r; f32 rows -> slot-scatter: Cf (slot<4096) / Cb-as-f32 (>=4096)
template<int MODE>
__global__ __launch_bounds__(256) void bgemm_kernel(
    const us16* __restrict__ A, const us16* __restrict__ Bt,
    float* __restrict__ Cf, us16* __restrict__ Cb,
    int M, int N, int Kd, int lda, int ldb, int ldc,
    const int* __restrict__ cnt, const int* __restrict__ base,
    const int* __restrict__ idx_list, i64 bstride)
{
    int ne = M, rowbase = 0;
    const int* il = nullptr;
    if (MODE != 0) {
        int e = blockIdx.z;
        ne = cnt[e];
        il = idx_list + (i64)e * T_;
        Bt += (i64)e * bstride;
        rowbase = base[e];
    }
    int row0 = blockIdx.y * 128;
    if (row0 >= ne) return;
    int col0 = blockIdx.x * 128;

    __shared__ us16 As[128 * 32];
    __shared__ us16 Bs[128 * 32];
    int tid = threadIdx.x;

    int r4 = tid >> 2, sseg = tid & 3;
    i64 arow0, arow1;
    {
        int g0 = row0 + r4, g1 = row0 + r4 + 64;
        int c0 = (g0 < ne) ? g0 : (ne - 1);
        int c1 = (g1 < ne) ? g1 : (ne - 1);
        if (MODE == 0)      { arow0 = (i64)g0 * lda;             arow1 = (i64)g1 * lda; }
        else if (MODE == 1) { arow0 = (i64)il[c0] * lda;         arow1 = (i64)il[c1] * lda; }
        else                { arow0 = (i64)(rowbase + c0) * lda; arow1 = (i64)(rowbase + c1) * lda; }
    }
    i64 brow0 = (i64)(col0 + r4) * ldb;
    i64 brow1 = brow0 + (i64)64 * ldb;
    int wa = tid * 8;

    int lane = tid & 63, w = tid >> 6;
    int wm = w >> 1, wn = w & 1;
    int cl = lane & 15, kg = lane >> 4;
    int aoff = (wm * 64 + cl) * 32 + kg * 8;
    int boff = (wn * 64 + cl) * 32 + kg * 8;

    f32x4 acc[4][4];
#pragma unroll
    for (int m = 0; m < 4; ++m)
#pragma unroll
        for (int n = 0; n < 4; ++n) {
            f32x4 z = {0.f, 0.f, 0.f, 0.f};
            acc[m][n] = z;
        }

    int so = sseg * 8;
    uint4 pa0 = *(const uint4*)&A[arow0 + so];
    uint4 pa1 = *(const uint4*)&A[arow1 + so];
    uint4 pb0 = *(const uint4*)&Bt[brow0 + so];
    uint4 pb1 = *(const uint4*)&Bt[brow1 + so];

    for (int k0 = 0; k0 < Kd; k0 += 32) {
        __syncthreads();
        *(uint4*)&As[wa]        = pa0;
        *(uint4*)&As[wa + 2048] = pa1;
        *(uint4*)&Bs[wa]        = pb0;
        *(uint4*)&Bs[wa + 2048] = pb1;
        __syncthreads();
        int kn = (k0 + 32 < Kd) ? k0 + 32 : Kd - 32;
        pa0 = *(const uint4*)&A[arow0 + kn + so];
        pa1 = *(const uint4*)&A[arow1 + kn + so];
        pb0 = *(const uint4*)&Bt[brow0 + kn + so];
        pb1 = *(const uint4*)&Bt[brow1 + kn + so];

        bf16x8 af[4], bfr[4];
#pragma unroll
        for (int m = 0; m < 4; ++m)
            af[m] = *(const bf16x8*)&As[aoff + m * 16 * 32];
#pragma unroll
        for (int n = 0; n < 4; ++n)
            bfr[n] = *(const bf16x8*)&Bs[boff + n * 16 * 32];
#pragma unroll
        for (int m = 0; m < 4; ++m)
#pragma unroll
            for (int n = 0; n < 4; ++n)
                acc[m][n] = __builtin_amdgcn_mfma_f32_16x16x32_bf16(af[m], bfr[n], acc[m][n], 0, 0, 0);
    }

#pragma unroll
    for (int m = 0; m < 4; ++m) {
#pragma unroll
        for (int j = 0; j < 4; ++j) {
            int r = row0 + wm * 64 + m * 16 + kg * 4 + j;
            if (MODE == 1) {
                if (r < ne) {
                    i64 ro = (i64)(rowbase + r) * ldc + col0 + wn * 64 + cl;
#pragma unroll
                    for (int n = 0; n < 4; ++n)
                        Cb[ro + n * 16] = f2b(silu_f(acc[m][n][j]));
                }
            } else if (MODE == 2) {
                if (r < ne) {
                    int slot = rowbase + r;
                    float* dst = (slot < 4096) ? (Cf + (i64)slot * ldc)
                                               : ((float*)Cb + (i64)(slot - 4096) * ldc);
                    i64 co = col0 + wn * 64 + cl;
#pragma unroll
                    for (int n = 0; n < 4; ++n)
                        dst[co + n * 16] = acc[m][n][j];
                }
            }
        }
    }
}

// ---------------- causal MLA attention: one wave per 4 q-rows, online softmax -------------
// K transposed bf16 (coalesced per-d loads; bf16 K error provably averages out through the
// near-uniform softmax). Q/V/output f32. P redistributed k-space->d-space via per-wave LDS.
__global__ __launch_bounds__(256) void attn_kernel(
    const float* __restrict__ Q, const us16* __restrict__ Kt,
    const float* __restrict__ Vb, float* __restrict__ O)
{
    int wave = threadIdx.x >> 6, lane = threadIdx.x & 63;
    int id = blockIdx.x * 4 + wave;          // [0, B*H*S/4)
    int q0 = (id & (S_ / 4 - 1)) * 4;
    int h  = (id >> 9) & (H_ - 1);
    int b  = id >> 13;
    const us16*  Kp = Kt + ((i64)(b * H_ + h)) * DH_ * S_;   // [64][S]
    const float* Vp = Vb + (i64)b * S_ * D_ + h * DH_;       // [S][1024] + head off
    const float* Qp = Q  + ((i64)(b * S_ + q0)) * D_ + h * DH_;

    __shared__ float qs[4][4][64];   // [wave][qq][d]
    __shared__ float ps[4][4][64];   // [wave][qq][k]
#pragma unroll
    for (int qq = 0; qq < 4; ++qq)
        qs[wave][qq][lane] = Qp[(i64)qq * D_ + lane];
    __builtin_amdgcn_wave_barrier();

    float m[4] = {-INFINITY, -INFINITY, -INFINITY, -INFINITY};
    float l[4] = {0.f, 0.f, 0.f, 0.f};
    float o[4] = {0.f, 0.f, 0.f, 0.f};
    int qmax = q0 + 3;

    for (int k0 = 0; k0 <= qmax; k0 += 64) {
        const us16* kcol = Kp + k0 + lane;
        float acc[4] = {0.f, 0.f, 0.f, 0.f};
#pragma unroll
        for (int d = 0; d < 64; d += 4) {
            float kv0 = b2f(kcol[(i64)(d + 0) * S_]);
            float kv1 = b2f(kcol[(i64)(d + 1) * S_]);
            float kv2 = b2f(kcol[(i64)(d + 2) * S_]);
            float kv3 = b2f(kcol[(i64)(d + 3) * S_]);
#pragma unroll
            for (int qq = 0; qq < 4; ++qq) {
                float4 qv = *(const float4*)&qs[wave][qq][d];   // LDS broadcast
                acc[qq] += kv0 * qv.x + kv1 * qv.y + kv2 * qv.z + kv3 * qv.w;
            }
        }
        int kj = k0 + lane;
#pragma unroll
        for (int qq = 0; qq < 4; ++qq) {
            float sc = (kj <= q0 + qq) ? acc[qq] * 0.125f : -INFINITY;
            float mn = fmaxf(m[qq], wmax(sc));
            float p  = __expf(sc - mn);          // masked lanes: 0
            float sm = wsum(p);
            float so = __expf(m[qq] - mn);       // first chunk: 0
            l[qq] = l[qq] * so + sm;
            o[qq] *= so;
            m[qq] = mn;
            ps[wave][qq][lane] = p;
        }
        __builtin_amdgcn_wave_barrier();
        const float* vrow = Vp + lane;
        int jlim = qmax - k0;
        for (int j = 0; j < 64 && j <= jlim; j += 4) {
            int r0 = k0 + j;
            int r1 = min(k0 + j + 1, qmax);
            int r2 = min(k0 + j + 2, qmax);
            int r3 = min(k0 + j + 3, qmax);
            float v0 = vrow[(i64)r0 * D_];
            float v1 = vrow[(i64)r1 * D_];
            float v2 = vrow[(i64)r2 * D_];
            float v3 = vrow[(i64)r3 * D_];
#pragma unroll
            for (int qq = 0; qq < 4; ++qq) {
                float4 pv = *(const float4*)&ps[wave][qq][j];   // LDS broadcast
                o[qq] += pv.x * v0 + pv.y * v1 + pv.z * v2 + pv.w * v3;
            }
        }
        __builtin_amdgcn_wave_barrier();
    }
#pragma unroll
    for (int qq = 0; qq < 4; ++qq)
        O[((i64)(b * S_ + q0 + qq)) * D_ + h * DH_ + lane] = o[qq] / l[qq];
}

// ------- gating: f32 x2 -> inline LN2 -> logits -> top2 -> renorm -> expert lists -------
// Fully-f32 gate path: bf16 anywhere here flips top-2 routing vs the f32 reference.
__global__ __launch_bounds__(256) void gate_kernel(
    const float* __restrict__ x2, const float* __restrict__ lnw, const float* __restrict__ lnb,
    const float* __restrict__ gW,
    int* __restrict__ cnt, int* __restrict__ idx_list,
    int2* __restrict__ tokinfo, float2* __restrict__ tokgate)
{
    int wave = threadIdx.x >> 6, lane = threadIdx.x & 63;
    int t = blockIdx.x * 4 + wave;
    const float* xr = x2 + (i64)t * D_;
    float xv[16];
    float s = 0.f, ss = 0.f;
#pragma unroll
    for (int it = 0; it < 16; ++it) {
        float v = xr[it * 64 + lane];
        xv[it] = v;
        s += v; ss += v * v;
    }
    s = wsum(s); ss = wsum(ss);
    float mu   = s * (1.f / D_);
    float var  = ss * (1.f / D_) - mu * mu;
    float rstd = rsqrtf(var + 1e-5f);
    float acc[8] = {0, 0, 0, 0, 0, 0, 0, 0};
#pragma unroll
    for (int it = 0; it < 16; ++it) {
        int d = it * 64 + lane;
        float hv = (xv[it] - mu) * rstd * lnw[d] + lnb[d];
        float4 g0 = ((const float4*)gW)[d * 2 + 0];
        float4 g1 = ((const float4*)gW)[d * 2 + 1];
        acc[0] += hv * g0.x; acc[1] += hv * g0.y; acc[2] += hv * g0.z; acc[3] += hv * g0.w;
        acc[4] += hv * g1.x; acc[5] += hv * g1.y; acc[6] += hv * g1.z; acc[7] += hv * g1.w;
    }
#pragma unroll
    for (int e = 0; e < 8; ++e) acc[e] = wsum(acc[e]);
    if (lane == 0) {
        float m = acc[0]; int i0 = 0;
        for (int e = 1; e < 8; ++e) if (acc[e] > m) { m = acc[e]; i0 = e; }  // ties: lowest idx
        float m2 = -INFINITY; int i1 = 0;
        for (int e = 0; e < 8; ++e) if (e != i0 && acc[e] > m2) { m2 = acc[e]; i1 = e; }
        float e1 = __expf(m2 - m);
        float g0 = 1.f / (1.f + e1);            // renormalized top-2 (denominators cancel)
        float g1 = e1 / (1.f + e1);
        int p0 = atomicAdd(&cnt[i0], 1);
        idx_list[(i64)i0 * T_ + p0] = t;
        int p1 = atomicAdd(&cnt[i1], 1);
        idx_list[(i64)i1 * T_ + p1] = t;
        tokinfo[t] = make_int2((i0 << 16) | p0, (i1 << 16) | p1);
        tokgate[t] = make_float2(g0, g1);
    }
}

__global__ void prefix_kernel(const int* __restrict__ cnt, int* __restrict__ base)
{
    if (threadIdx.x == 0 && blockIdx.x == 0) {
        int s = 0;
        for (int e = 0; e < E_; ++e) { base[e] = s; s += cnt[e]; }
        base[E_] = s;
    }
}

// ------- final merge: out[t] += g0*moe[slot0] + g1*moe[slot1] (coalesced, no atomics) -------
__global__ __launch_bounds__(256) void moe_merge_kernel(
    const float* __restrict__ moeA, const float* __restrict__ moeB,
    const int* __restrict__ basep, const int2* __restrict__ tokinfo,
    const float2* __restrict__ tokgate, float* __restrict__ out)
{
    int t = blockIdx.x, tid = threadIdx.x;
    int2 ti = tokinfo[t];
    float2 g = tokgate[t];
    int s0 = basep[ti.x >> 16] + (ti.x & 0xffff);
    int s1 = basep[ti.y >> 16] + (ti.y & 0xffff);
    const float* r0 = (s0 < 4096) ? moeA + (i64)s0 * D_ : moeB + (i64)(s0 - 4096) * D_;
    const float* r1 = (s1 < 4096) ? moeA + (i64)s1 * D_ : moeB + (i64)(s1 - 4096) * D_;
    float4 a = ((const float4*)r0)[tid];
    float4 b = ((const float4*)r1)[tid];
    float4 o = ((float4*)(out + (i64)t * D_))[tid];
    o.x += g.x * a.x + g.y * b.x;
    o.y += g.x * a.y + g.y * b.y;
    o.z += g.x * a.z + g.y * b.z;
    o.w += g.x * a.w + g.y * b.w;
    ((float4*)(out + (i64)t * D_))[tid] = o;
}

extern "C" void kernel_launch(void* const* d_in, const int* in_sizes, int n_in,
                              void* d_out, int out_size, void* d_ws, size_t ws_size,
                              hipStream_t stream)
{
    const float* x    = (const float*)d_in[0];
    const float* ln1w = (const float*)d_in[1];
    const float* ln1b = (const float*)d_in[2];
    const float* Wq   = (const float*)d_in[3];
    const float* Wdkv = (const float*)d_in[4];
    const float* Wuk  = (const float*)d_in[5];
    const float* Wuv  = (const float*)d_in[6];
    const float* Wo   = (const float*)d_in[7];
    const float* ln2w = (const float*)d_in[8];
    const float* ln2b = (const float*)d_in[9];
    const float* gW   = (const float*)d_in[10];
    const float* W1   = (const float*)d_in[11];
    const float* W2   = (const float*)d_in[12];

    float* out = (float*)d_out;               // [T,1024] x_out
    float* nkv = out + (i64)T_ * D_;          // [T,256]  new_kv
    char* wsb = (char*)d_ws;

    // region A: h1f32 -> Kt(bf16,8M) -> h2bf(8M) -> moeB
    float* h1f  = (float*)(wsb + WOFF_A);
    us16*  Ktb  = (us16*)(wsb + WOFF_A);
    us16*  h2bf = (us16*)(wsb + WOFF_A);
    float* moeB = (float*)(wsb + WOFF_A);
    // region B: q -> attn_proj -> moeA
    float* qb   = (float*)(wsb + WOFF_B);
    float* moeA = (float*)(wsb + WOFF_B);
    // region C: k -> attn-out -> hid (hid spans C+D contiguously)
    float* kf   = (float*)(wsb + WOFF_C);
    float* aof  = (float*)(wsb + WOFF_C);
    us16*  hid  = (us16*)(wsb + WOFF_C);
    // region D: v
    float* vb   = (float*)(wsb + WOFF_D);
    // split MLA weights
    us16* WqH   = (us16*)(wsb + WOFF_WSPL);
    us16* WqL   = (us16*)(wsb + WOFF_WSPL + (2LL<<20));
    us16* WoH   = (us16*)(wsb + WOFF_WSPL + (4LL<<20));
    us16* WoL   = (us16*)(wsb + WOFF_WSPL + (6LL<<20));
    us16* WdkvH = (us16*)(wsb + WOFF_WSPL + (8LL<<20));
    us16* WdkvL = (us16*)(wsb + WOFF_WSPL + (8LL<<20) + 524288);
    us16* WukH  = (us16*)(wsb + WOFF_WSPL + (9LL<<20));
    us16* WukL  = (us16*)(wsb + WOFF_WSPL + (9LL<<20) + 524288);
    us16* WuvH  = (us16*)(wsb + WOFF_WSPL + (10LL<<20));
    us16* WuvL  = (us16*)(wsb + WOFF_WSPL + (10LL<<20) + 524288);
    us16* W1T   = (us16*)(wsb + WOFF_W1T);
    us16* W2T   = (us16*)(wsb + WOFF_W2T);
    char* lists = wsb + WOFF_LISTS;
    int*    cnt     = (int*)lists;
    int*    basep   = (int*)(lists + 64);
    int*    idxl    = (int*)(lists + 128);                  // int[8*4096] = 128 KB
    int2*   tokinfo = (int2*)(lists + 128 + 131072);        // 32 KB
    float2* tokgate = (float2*)(lists + 128 + 131072 + 32768);

    // 0) weight preprocessing
    wtrans_split_kernel<<<dim3(32, 32), 256, 0, stream>>>(Wq,   WqH,   WqL,   1024, 1024);
    wtrans_split_kernel<<<dim3(8, 32),  256, 0, stream>>>(Wdkv, WdkvH, WdkvL, 1024, 256);
    wtrans_split_kernel<<<dim3(32, 8),  256, 0, stream>>>(Wuk,  WukH,  WukL,  256, 1024);
    wtrans_split_kernel<<<dim3(32, 8),  256, 0, stream>>>(Wuv,  WuvH,  WuvL,  256, 1024);
    wtrans_split_kernel<<<dim3(32, 32), 256, 0, stream>>>(Wo,   WoH,   WoL,   1024, 1024);
    wtrans_kernel<<<dim3(64, 32, 8), 256, 0, stream>>>(W1, W1T, 1024, 2048);
    wtrans_kernel<<<dim3(32, 64, 8), 256, 0, stream>>>(W2, W2T, 2048, 1024);

    // 1) h1 = LN1(x)  (f32)
    add_ln_kernel<<<T_, 256, 0, stream>>>(x, nullptr, ln1w, ln1b, nullptr, h1f, nullptr);
    // 2) q = h1 @ Wq  (split)
    sgemm_split_kernel<<<dim3(8, 32), 256, 0, stream>>>(h1f, WqH, WqL, qb, 1024, 1024, 1024, 1024, 1024);
    // 3) c_kv = h1 @ Wdkv -> nkv (split; near-f32 -> exact-ish new_kv output)
    sgemm_split_kernel<<<dim3(2, 32), 256, 0, stream>>>(h1f, WdkvH, WdkvL, nkv, 256, 1024, 1024, 1024, 256);
    // 4) k = c_kv @ Wuk ; v = c_kv @ Wuv  (split, f32 out)
    sgemm_split_kernel<<<dim3(8, 32), 256, 0, stream>>>(nkv, WukH, WukL, kf, 1024, 256, 256, 256, 1024);
    sgemm_split_kernel<<<dim3(8, 32), 256, 0, stream>>>(nkv, WuvH, WuvL, vb, 1024, 256, 256, 256, 1024);
    // 4b) Kt = per-head transpose of k -> bf16 (h1 region dead)
    ktrans_kernel<<<dim3(S_ / 32, 2, 32), 256, 0, stream>>>(kf, Ktb);
    // 5) attention -> f32 head-concat into aof (kf dead)
    attn_kernel<<<B_ * H_ * S_ / 16, 256, 0, stream>>>(qb, Ktb, vb, aof);
    // 6) attn_proj = attnO @ Wo (split, into qb; q dead)
    sgemm_split_kernel<<<dim3(8, 32), 256, 0, stream>>>(aof, WoH, WoL, qb, 1024, 1024, 1024, 1024, 1024);
    // 7) x2 = x + attn_proj -> d_out ; h2 bf16 -> h2bf (Kt dead)
    add_ln_kernel<<<T_, 256, 0, stream>>>(x, qb, ln2w, ln2b, out, nullptr, h2bf);
    // 8) gating from f32 x2 (inline LN2) + expert compaction
    hipMemsetAsync(cnt, 0, E_ * sizeof(int), stream);
    gate_kernel<<<T_ / 4, 256, 0, stream>>>(out, ln2w, ln2b, gW, cnt, idxl, tokinfo, tokgate);
    prefix_kernel<<<1, 64, 0, stream>>>(cnt, basep);
    // 9) hidden = bf16(silu(gather(h2) @ W1[e]))  (aof/vb dead -> hid spans C+D)
    bgemm_kernel<1><<<dim3(16, 32, 8), 256, 0, stream>>>(h2bf, W1T, nullptr, hid,
        T_, 2048, 1024, 1024, 1024, 2048, cnt, basep, idxl, (i64)DFF_ * D_);
    // 10) moe[slot] = hidden @ W2[e]  (non-atomic slot scatter: moeA=B region, moeB=A region)
    bgemm_kernel<2><<<dim3(8, 32, 8), 256, 0, stream>>>(hid, W2T, moeA, (us16*)moeB,
        T_, 1024, 2048, 2048, 2048, 1024, cnt, basep, idxl, (i64)D_ * DFF_);
    // 11) out[t] += g0*moe[slot0(t)] + g1*moe[slot1(t)]
    moe_merge_kernel<<<T_, 256, 0, stream>>>(moeA, moeB, basep, tokinfo, tokgate, out);
}